// Round 8
// baseline (179.181 us; speedup 1.0000x reference)
//
#include <hip/hip_runtime.h>
#include <math.h>

#define DK 32
#define OUT_DIM 32

typedef float    f32x4 __attribute__((ext_vector_type(4)));
typedef _Float16 h2    __attribute__((ext_vector_type(2)));
typedef _Float16 h8    __attribute__((ext_vector_type(8)));

#if __has_builtin(__builtin_amdgcn_exp2f)
#define EXP2F(x) __builtin_amdgcn_exp2f(x)
#else
#define EXP2F(x) exp2f(x)
#endif

__device__ __forceinline__ h2 as_h2(unsigned u) {
    union { unsigned u; h2 h; } v; v.u = u; return v.h;
}
__device__ __forceinline__ unsigned as_u32(h2 h) {
    union { unsigned u; h2 h; } v; v.h = h; return v.u;
}

// int8 dot4 (HW v_dot4_i32_i8 when available)
#if __has_builtin(__builtin_amdgcn_sdot4)
__device__ __forceinline__ int dot4i8(unsigned a, unsigned b) {
    return __builtin_amdgcn_sdot4((int)a, (int)b, 0, false);
}
#else
__device__ __forceinline__ int dot4i8(unsigned a, unsigned b) {
    int s = (int)(char)(a) * (int)(char)(b);
    s += (int)(char)(a >> 8)  * (int)(char)(b >> 8);
    s += (int)(char)(a >> 16) * (int)(char)(b >> 16);
    s += (int)(char)(a >> 24) * (int)(char)(b >> 24);
    return s;
}
#endif

// ---- int8 quantizers -------------------------------------------------------
__device__ __forceinline__ unsigned q8b(float x, float r) {      // signed
    int i = (int)rintf(x * r);
    i = min(127, max(-127, i));
    return (unsigned)(i & 255);
}
__device__ __forceinline__ unsigned pack8x4(float4 f, float r) {
    return q8b(f.x, r) | (q8b(f.y, r) << 8) |
           (q8b(f.z, r) << 16) | (q8b(f.w, r) << 24);
}
__device__ __forceinline__ unsigned q8bu(float x, float r) {     // biased +128
    int i = (int)rintf(x * r);
    i = min(127, max(-127, i));
    return (unsigned)(i + 128);
}
__device__ __forceinline__ unsigned pack8x4u(float4 f, float r) {
    return q8bu(f.x, r) | (q8bu(f.y, r) << 8) |
           (q8bu(f.z, r) << 16) | (q8bu(f.w, r) << 24);
}

// R19 prep.
// Post-mortem R14-R18: all scheduling attacks null; the kernel sits on a
// per-CU L2-miss concurrency wall (~15 outstanding misses/CU) because the
// gather table (6.4-12.8 MB) churns through the 4 MB per-XCD L2 -> every
// gather is a ~700 cy miss. Fix: SPLIT K and V into separate 3.2 MB tables
// (each < 4 MB -> L2-resident per XCD) and gather them in two separate
// DISPATCHES (temporal separation). K8: N x 32 B signed-int8 rows; V8:
// N x 32 B biased-u8 rows (v+128, bias removed analytically via sum-of-
// weights); SC: per-node f16 {sK, sV} (400 KB, always hot).
__global__ void prep_kernel(const int* __restrict__ dst,
                            const float4* __restrict__ K4,
                            const float4* __restrict__ V4,
                            int E, int N,
                            int* __restrict__ row_ptr,
                            unsigned* __restrict__ K8,
                            unsigned* __restrict__ V8,
                            unsigned* __restrict__ SC) {
    const int t  = blockIdx.x * blockDim.x + threadIdx.x;
    const int e0 = t * 4;
    if (e0 < E) {
        int cur[4];
        if (e0 + 4 <= E) {
            const int4 dd = *(const int4*)(dst + e0);
            cur[0] = dd.x; cur[1] = dd.y; cur[2] = dd.z; cur[3] = dd.w;
        } else {
#pragma unroll
            for (int k = 0; k < 4; ++k)
                cur[k] = (e0 + k < E) ? dst[e0 + k] : 0;
        }
        int prev = (e0 == 0) ? -1 : dst[e0 - 1];
#pragma unroll
        for (int k = 0; k < 4; ++k) {
            const int ee = e0 + k;
            if (ee < E) {
                for (int j = prev + 1; j <= cur[k]; ++j) row_ptr[j] = ee;
                if (ee == E - 1)
                    for (int j = cur[k] + 1; j <= N; ++j) row_ptr[j] = E;
                prev = cur[k];
            }
        }
    }
    if (t < N) {
        float4 kf[8], vf[8];
#pragma unroll
        for (int u = 0; u < 8; ++u) { kf[u] = K4[t * 8 + u]; vf[u] = V4[t * 8 + u]; }
        float mk = 0.0f, mv = 0.0f;
#pragma unroll
        for (int u = 0; u < 8; ++u) {
            mk = fmaxf(mk, fmaxf(fmaxf(fabsf(kf[u].x), fabsf(kf[u].y)),
                                 fmaxf(fabsf(kf[u].z), fabsf(kf[u].w))));
            mv = fmaxf(mv, fmaxf(fmaxf(fabsf(vf[u].x), fabsf(vf[u].y)),
                                 fmaxf(fabsf(vf[u].z), fabsf(vf[u].w))));
        }
        const float rk = (mk > 0.0f) ? 127.0f / mk : 0.0f;
        const float rv = (mv > 0.0f) ? 127.0f / mv : 0.0f;
        uint4* ko = (uint4*)(K8 + t * 8);
        uint4* vo = (uint4*)(V8 + t * 8);
#pragma unroll
        for (int u2 = 0; u2 < 2; ++u2) {
            uint4 ok, ov;
            ok.x = pack8x4 (kf[4 * u2],     rk);
            ok.y = pack8x4 (kf[4 * u2 + 1], rk);
            ok.z = pack8x4 (kf[4 * u2 + 2], rk);
            ok.w = pack8x4 (kf[4 * u2 + 3], rk);
            ov.x = pack8x4u(vf[4 * u2],     rv);
            ov.y = pack8x4u(vf[4 * u2 + 1], rv);
            ov.z = pack8x4u(vf[4 * u2 + 2], rv);
            ov.w = pack8x4u(vf[4 * u2 + 3], rv);
            ko[u2] = ok;
            vo[u2] = ov;
        }
        h2 s;
        s.x = (_Float16)(mk * (1.0f / 127.0f));   // K dequant scale
        s.y = (_Float16)(mv * (1.0f / 127.0f));   // V dequant scale
        SC[t] = as_u32(s);
    }
}

// Fallback-path row_ptr builder (ws too small for packed tables).
__global__ void build_row_ptr_kernel(const int* __restrict__ dst, int E, int N,
                                     int* __restrict__ row_ptr) {
    int e = blockIdx.x * blockDim.x + threadIdx.x;
    if (e >= E) return;
    int cur  = dst[e];
    int prev = (e == 0) ? -1 : dst[e - 1];
    for (int j = prev + 1; j <= cur; ++j) row_ptr[j] = e;
    if (e == E - 1) {
        for (int j = cur + 1; j <= N; ++j) row_ptr[j] = E;
    }
}

// R19 pass 1: scores + softmax denominator. Gathers ONLY the 3.2 MB K8
// table (L2-resident per XCD) + hot SC. One node/wave, 8-slot x 8-chunk
// lanes, straight-line prologue. Dot via v_dot4_i32_i8 on per-node int8-
// quantized q. Writes unnormalized w (f16) per edge + 1/l per node.
__global__ __launch_bounds__(256) void gat_score_kernel(
    const float* __restrict__ X, const unsigned* __restrict__ K8,
    const unsigned* __restrict__ SC, const int* __restrict__ src,
    const int* __restrict__ row_ptr, unsigned short* __restrict__ wbuf,
    float* __restrict__ linv, int N) {

    const int tid  = threadIdx.x;
    const int w    = tid >> 6;
    const int lane = tid & 63;
    const int g    = lane >> 3;   // edge slot 0..7
    const int c    = lane & 7;    // dim chunk 0..7 (4 dims each)

    const int n = blockIdx.x * 4 + w;

    const int B    = __builtin_amdgcn_readfirstlane(row_ptr[min(n, N)]);
    const int En   = __builtin_amdgcn_readfirstlane(row_ptr[min(n + 1, N)]);
    const int deg  = En - B;
    const int dcap = max(En - 1, 0);
    const int T    = (deg + 7) >> 3;

    // per-node int8 quantization of q (dims 4c..4c+3 per lane)
    const float4 qf = ((const float4*)X)[min(n, N - 1) * 8 + c];
    float mq = fmaxf(fmaxf(fabsf(qf.x), fabsf(qf.y)),
                     fmaxf(fabsf(qf.z), fabsf(qf.w)));
    mq = fmaxf(mq, __shfl_xor(mq, 1));
    mq = fmaxf(mq, __shfl_xor(mq, 2));
    mq = fmaxf(mq, __shfl_xor(mq, 4));
    const float rq = (mq > 0.0f) ? 127.0f / mq : 0.0f;
    const unsigned qd = pack8x4(qf, rq);
    // p = si * sK * sQ * (1/32) * log2(e);  cS = sQ * (1/32) * log2(e)
    const float cS = mq * (0.03125f * 1.44269504f / 127.0f);

    float l = 0.0f;

    auto step = [&](unsigned kd, unsigned sc, int t) {
        int si = dot4i8(kd, qd);
        si += __shfl_xor(si, 1);
        si += __shfl_xor(si, 2);
        si += __shfl_xor(si, 4);
        const float sK = (float)as_h2(sc).x;
        const float p  = (float)si * (sK * cS);
        const bool valid = (t * 8 + g) < deg;
        const float wt = valid ? EXP2F(p) : 0.0f;
        l += wt;
        if (valid && c == 0) {          // one lane per edge stores w (f16)
            h2 hw; hw.x = (_Float16)wt; hw.y = hw.x;
            wbuf[B + t * 8 + g] = (unsigned short)as_u32(hw);
        }
    };

    if (T > 0) {
        const int base = B + g;
        const int s0 = src[min(base,      dcap)];
        const int s1 = src[min(base + 8,  dcap)];
        const int s2 = src[min(base + 16, dcap)];
        const int s3 = src[min(base + 24, dcap)];
        unsigned k0 = 0, k1 = 0, k2 = 0, k3 = 0;
        unsigned x0 = 0, x1 = 0, x2 = 0, x3 = 0;
        k0 = K8[s0 * 8 + c];               x0 = SC[s0];
        if (T > 1) { k1 = K8[s1 * 8 + c];  x1 = SC[s1]; }
        if (T > 2) { k2 = K8[s2 * 8 + c];  x2 = SC[s2]; }
        if (T > 3) { k3 = K8[s3 * 8 + c];  x3 = SC[s3]; }

        step(k0, x0, 0);
        if (T > 1) step(k1, x1, 1);
        if (T > 2) step(k2, x2, 2);
        if (T > 3) step(k3, x3, 3);
        for (int t = 4; t < T; ++t) {     // rare deg > 32 tail
            const int sx = src[min(B + t * 8 + g, dcap)];
            step(K8[sx * 8 + c], SC[sx], t);
        }
    }

    l += __shfl_xor(l, 8);
    l += __shfl_xor(l, 16);
    l += __shfl_xor(l, 32);
    if (lane == 0 && n < N) {
        linv[n] = (deg > 0) ? (1.0f / l) : 0.0f;
    }
}

// R19 pass 2: weighted V aggregation + projection. Gathers ONLY the 3.2 MB
// V8 table (L2-resident per XCD) + hot SC; w streams in from wbuf. Biased-
// u8 decode: acc += wv*Vb, bias removed via 128*sum(wv). Verified MFMA
// projection epilogue (A-tile 16x128, Wo replicated along K) unchanged.
__global__ __launch_bounds__(512) void gat_pv_kernel(
    const unsigned* __restrict__ V8, const unsigned* __restrict__ SC,
    const int* __restrict__ src, const int* __restrict__ row_ptr,
    const unsigned short* __restrict__ wbuf, const float* __restrict__ linv,
    const float* __restrict__ Wo, const float* __restrict__ bo,
    float* __restrict__ out, int N) {

    __shared__ uint4 s_part[16 * 17];   // 16-row A-tile, row stride 17 (pad)

    const int tid  = threadIdx.x;
    const int w    = tid >> 6;    // wave 0..7 = node offset in block
    const int lane = tid & 63;
    const int g    = lane >> 3;   // edge slot 0..7
    const int c    = lane & 7;    // dim chunk 0..7

    const int n_blk = blockIdx.x * 8;
    const int n     = n_blk + w;

    if (tid < 136) {                    // zero A-tile rows 8..15
        uint4 z; z.x = 0; z.y = 0; z.z = 0; z.w = 0;
        s_part[136 + tid] = z;
    }

    const int B    = __builtin_amdgcn_readfirstlane(row_ptr[min(n, N)]);
    const int En   = __builtin_amdgcn_readfirstlane(row_ptr[min(n + 1, N)]);
    const int deg  = En - B;
    const int dcap = max(En - 1, 0);
    const int T    = (deg + 7) >> 3;

    const float inv = linv[min(n, N - 1)];   // broadcast load (0 if deg==0)

    f32x4 acc = {0.0f, 0.0f, 0.0f, 0.0f};
    float sw = 0.0f;                          // sum of wv (for bias removal)

    auto step = [&](unsigned vd, unsigned sc, unsigned short wl, int t) {
        const bool valid = (t * 8 + g) < deg;
        const float wf = (float)as_h2((unsigned)wl).x;
        const float sV = (float)as_h2(sc).y;
        const float wv = valid ? wf * sV : 0.0f;
        sw += wv;
        acc.x = fmaf(wv, (float)(vd & 255u),         acc.x);
        acc.y = fmaf(wv, (float)((vd >> 8) & 255u),  acc.y);
        acc.z = fmaf(wv, (float)((vd >> 16) & 255u), acc.z);
        acc.w = fmaf(wv, (float)(vd >> 24),          acc.w);
    };

    if (T > 0) {
        const int base = B + g;
        const int s0 = src[min(base,      dcap)];
        const int s1 = src[min(base + 8,  dcap)];
        const int s2 = src[min(base + 16, dcap)];
        const int s3 = src[min(base + 24, dcap)];
        unsigned v0 = 0, v1 = 0, v2 = 0, v3 = 0;
        unsigned x0 = 0, x1 = 0, x2 = 0, x3 = 0;
        unsigned short w0 = 0, w1 = 0, w2 = 0, w3 = 0;
        v0 = V8[s0 * 8 + c];  x0 = SC[s0];  w0 = wbuf[min(base, dcap)];
        if (T > 1) { v1 = V8[s1 * 8 + c];  x1 = SC[s1];
                     w1 = wbuf[min(base + 8,  dcap)]; }
        if (T > 2) { v2 = V8[s2 * 8 + c];  x2 = SC[s2];
                     w2 = wbuf[min(base + 16, dcap)]; }
        if (T > 3) { v3 = V8[s3 * 8 + c];  x3 = SC[s3];
                     w3 = wbuf[min(base + 24, dcap)]; }

        step(v0, x0, w0, 0);
        if (T > 1) step(v1, x1, w1, 1);
        if (T > 2) step(v2, x2, w2, 2);
        if (T > 3) step(v3, x3, w3, 3);
        for (int t = 4; t < T; ++t) {     // rare deg > 32 tail
            const int e = B + t * 8 + g;
            const int sx = src[min(e, dcap)];
            step(V8[sx * 8 + c], SC[sx], wbuf[min(e, dcap)], t);
        }
    }

    // fold to 4 slot-pair partials; sw fully reduced (needed for bias)
    acc.x += __shfl_xor(acc.x, 8);
    acc.y += __shfl_xor(acc.y, 8);
    acc.z += __shfl_xor(acc.z, 8);
    acc.w += __shfl_xor(acc.w, 8);
    sw += __shfl_xor(sw, 8);
    sw += __shfl_xor(sw, 16);
    sw += __shfl_xor(sw, 32);

    // per-partial bias removal: 4 partials x (-32*sw) = -128*sw total
    const float bias = 32.0f * sw;
    h2 o01, o23;
    o01.x = (_Float16)((acc.x - bias) * inv);
    o01.y = (_Float16)((acc.y - bias) * inv);
    o23.x = (_Float16)((acc.z - bias) * inv);
    o23.y = (_Float16)((acc.w - bias) * inv);

    if ((g & 1) == 0) {                  // even slots hold pair sums
        unsigned* part32 = (unsigned*)s_part;
        const int off = w * 68 + (g >> 1) * 16 + c * 2;   // uint32 units
        part32[off]     = as_u32(o01);
        part32[off + 1] = as_u32(o23);
    }

    __syncthreads();

    // wave 0: projection for the block's 8 nodes via 16x16x32 f16 MFMA
    if (w == 0) {
        const int quad = lane >> 4;   // 0..3
        const int col  = lane & 15;

        union BF { h8 v; _Float16 u[8]; };
        BF bf0, bf1;
#pragma unroll
        for (int j2 = 0; j2 < 8; ++j2) {
            bf0.u[j2] = (_Float16)Wo[(quad * 8 + j2) * OUT_DIM + col];
            bf1.u[j2] = (_Float16)Wo[(quad * 8 + j2) * OUT_DIM + 16 + col];
        }
        const float bias0 = bo[col];
        const float bias1 = bo[16 + col];

        union AF { uint4 u; h8 v; };
        f32x4 C0 = {bias0, bias0, bias0, bias0};
        f32x4 C1 = {bias1, bias1, bias1, bias1};
#pragma unroll
        for (int cc = 0; cc < 4; ++cc) {
            AF a;
            a.u = s_part[col * 17 + cc * 4 + quad];      // ds_read_b128
            C0 = __builtin_amdgcn_mfma_f32_16x16x32_f16(a.v, bf0.v, C0, 0, 0, 0);
            C1 = __builtin_amdgcn_mfma_f32_16x16x32_f16(a.v, bf1.v, C1, 0, 0, 0);
        }
        // C/D layout: col = lane&15, row = quad*4 + reg (verified mapping)
        if (quad < 2) {                 // only rows 0..7 are real nodes
#pragma unroll
            for (int r = 0; r < 4; ++r) {
                const int n2 = n_blk + quad * 4 + r;
                if (n2 < N) {
                    out[n2 * OUT_DIM + col]      = C0[r];
                    out[n2 * OUT_DIM + 16 + col] = C1[r];
                }
            }
        }
    }
}

// ---- fallback (R4-proven fp32 path, used only if ws too small) ------------
__global__ __launch_bounds__(256) void gat_node_f32_kernel(
    const float* __restrict__ X, const float* __restrict__ Km,
    const float* __restrict__ Vm, const float* __restrict__ Wo,
    const float* __restrict__ bo, const int* __restrict__ src,
    const int* __restrict__ row_ptr, float* __restrict__ out, int N) {
    const int tid  = threadIdx.x;
    const int wave = tid >> 6;
    const int lane = tid & 63;
    const int g    = lane >> 3;
    const int c    = lane & 7;
    const int j    = lane & 31;
    const int half = lane >> 5;
    const int n = blockIdx.x * 4 + wave;
    if (n >= N) return;
    const int begin = row_ptr[n];
    const int end   = row_ptr[n + 1];
    const float4* X4 = (const float4*)X;
    const float4* K4 = (const float4*)Km;
    const float4* V4 = (const float4*)Vm;
    const float4 q4 = X4[n * 8 + c];
    float  l   = 0.0f;
    float4 acc = make_float4(0.0f, 0.0f, 0.0f, 0.0f);
    for (int e0 = begin; e0 < end; e0 += 16) {
        const int  ea = e0 + g;
        const int  eb = ea + 8;
        const bool va = ea < end;
        const bool vb = eb < end;
        const int sa = src[min(ea, end - 1)];
        const int sb = src[min(eb, end - 1)];
        const float4 ka  = K4[sa * 8 + c];
        const float4 kb  = K4[sb * 8 + c];
        const float4 vva = V4[sa * 8 + c];
        const float4 vvb = V4[sb * 8 + c];
        float pa = fmaf(ka.x, q4.x, fmaf(ka.y, q4.y, fmaf(ka.z, q4.z, ka.w * q4.w)));
        float pb = fmaf(kb.x, q4.x, fmaf(kb.y, q4.y, fmaf(kb.z, q4.z, kb.w * q4.w)));
        pa += __shfl_xor(pa, 1);  pb += __shfl_xor(pb, 1);
        pa += __shfl_xor(pa, 2);  pb += __shfl_xor(pb, 2);
        pa += __shfl_xor(pa, 4);  pb += __shfl_xor(pb, 4);
        const float wa = va ? __expf(pa * 0.03125f) : 0.0f;
        const float wb = vb ? __expf(pb * 0.03125f) : 0.0f;
        l += wa + wb;
        acc.x = fmaf(wa, vva.x, acc.x);  acc.y = fmaf(wa, vva.y, acc.y);
        acc.z = fmaf(wa, vva.z, acc.z);  acc.w = fmaf(wa, vva.w, acc.w);
        acc.x = fmaf(wb, vvb.x, acc.x);  acc.y = fmaf(wb, vvb.y, acc.y);
        acc.z = fmaf(wb, vvb.z, acc.z);  acc.w = fmaf(wb, vvb.w, acc.w);
    }
#pragma unroll
    for (int m = 8; m <= 32; m <<= 1) {
        l     += __shfl_xor(l, m);
        acc.x += __shfl_xor(acc.x, m);
        acc.y += __shfl_xor(acc.y, m);
        acc.z += __shfl_xor(acc.z, m);
        acc.w += __shfl_xor(acc.w, m);
    }
    const float inv = (end > begin) ? (1.0f / l) : 0.0f;
    float ag[4] = {acc.x, acc.y, acc.z, acc.w};
    float s = 0.0f;
#pragma unroll
    for (int k = 0; k < 32; ++k) {
        const float a = __int_as_float(
            __builtin_amdgcn_readlane(__float_as_int(ag[k & 3]), k >> 2));
        s = fmaf(a, Wo[k * OUT_DIM + j], s);
    }
    if (half == 0) {
        out[n * OUT_DIM + j] = fmaf(s, inv, bo[j]);
    }
}

extern "C" void kernel_launch(void* const* d_in, const int* in_sizes, int n_in,
                              void* d_out, int out_size, void* d_ws, size_t ws_size,
                              hipStream_t stream) {
    const float* X  = (const float*)d_in[0];
    const float* Km = (const float*)d_in[1];
    const float* Vm = (const float*)d_in[2];
    const float* Wo = (const float*)d_in[3];
    const float* bo = (const float*)d_in[4];
    const int* src  = (const int*)d_in[5];
    const int* dst  = (const int*)d_in[6];

    const int N = in_sizes[0] / DK;
    const int E = in_sizes[5];

    // ws layout: row_ptr | K8 (N*32B) | V8 (N*32B) | SC (N*4B) |
    //            wbuf (E*2B) | linv (N*4B)
    int* row_ptr = (int*)d_ws;
    const size_t k8_off  = (((size_t)(N + 1) * 4) + 127) & ~(size_t)127;
    const size_t v8_off  = ((k8_off + (size_t)N * 32) + 127) & ~(size_t)127;
    const size_t sc_off  = ((v8_off + (size_t)N * 32) + 127) & ~(size_t)127;
    const size_t wb_off  = ((sc_off + (size_t)N * 4) + 127) & ~(size_t)127;
    const size_t li_off  = ((wb_off + (size_t)E * 2) + 127) & ~(size_t)127;
    unsigned* K8 = (unsigned*)((char*)d_ws + k8_off);
    unsigned* V8 = (unsigned*)((char*)d_ws + v8_off);
    unsigned* SCt = (unsigned*)((char*)d_ws + sc_off);
    unsigned short* wbuf = (unsigned short*)((char*)d_ws + wb_off);
    float* linv = (float*)((char*)d_ws + li_off);
    const size_t need = li_off + (size_t)N * 4;
    float* out = (float*)d_out;

    const int tb = 256;

    if (ws_size >= need) {
        const int nE4   = (E + 3) / 4;
        const int prep_n = (nE4 > N) ? nE4 : N;
        prep_kernel<<<(prep_n + tb - 1) / tb, tb, 0, stream>>>(
            dst, (const float4*)Km, (const float4*)Vm, E, N,
            row_ptr, K8, V8, SCt);
        gat_score_kernel<<<(N + 3) / 4, 256, 0, stream>>>(
            X, K8, SCt, src, row_ptr, wbuf, linv, N);
        gat_pv_kernel<<<(N + 7) / 8, 512, 0, stream>>>(
            V8, SCt, src, row_ptr, wbuf, linv, Wo, bo, out, N);
    } else {
        build_row_ptr_kernel<<<(E + tb - 1) / tb, tb, 0, stream>>>(dst, E, N, row_ptr);
        const int grid = (N + 3) / 4;
        gat_node_f32_kernel<<<grid, 256, 0, stream>>>(X, Km, Vm, Wo, bo,
                                                      src, row_ptr, out, N);
    }
}

// Round 9
// 160.621 us; speedup vs baseline: 1.1155x; 1.1155x over previous
//
#include <hip/hip_runtime.h>
#include <math.h>

#define DK 32
#define OUT_DIM 32

typedef float    f32x4 __attribute__((ext_vector_type(4)));
typedef _Float16 h2    __attribute__((ext_vector_type(2)));
typedef _Float16 h8    __attribute__((ext_vector_type(8)));

#if __has_builtin(__builtin_amdgcn_exp2f)
#define EXP2F(x) __builtin_amdgcn_exp2f(x)
#else
#define EXP2F(x) exp2f(x)
#endif

__device__ __forceinline__ h2 as_h2(unsigned u) {
    union { unsigned u; h2 h; } v; v.u = u; return v.h;
}
__device__ __forceinline__ unsigned as_u32(h2 h) {
    union { unsigned u; h2 h; } v; v.h = h; return v.u;
}

// int8 dot4 with accumulator (HW v_dot4_i32_i8 when available)
#if __has_builtin(__builtin_amdgcn_sdot4)
#define SDOT4(a, b, c) __builtin_amdgcn_sdot4((int)(a), (int)(b), (c), false)
#else
__device__ __forceinline__ int sdot4_sw(unsigned a, unsigned b, int c) {
    c += (int)(char)(a)        * (int)(char)(b);
    c += (int)(char)(a >> 8)   * (int)(char)(b >> 8);
    c += (int)(char)(a >> 16)  * (int)(char)(b >> 16);
    c += (int)(char)(a >> 24)  * (int)(char)(b >> 24);
    return c;
}
#define SDOT4(a, b, c) sdot4_sw((a), (b), (c))
#endif

// ---- int8 quantizer (per-node scale, signed) -------------------------------
__device__ __forceinline__ unsigned q8b(float x, float r) {
    int i = (int)rintf(x * r);
    i = min(127, max(-127, i));
    return (unsigned)(i & 255);
}
__device__ __forceinline__ unsigned pack8x4(float4 f, float r) {
    return q8b(f.x, r) | (q8b(f.y, r) << 8) |
           (q8b(f.z, r) << 16) | (q8b(f.w, r) << 24);
}

// R20 prep.
// Post-mortem R19: the K-only node-centric score pass (L2-resident table)
// still took 46 us == the old fused kernel; VALUBusy ~60%. The binder is
// node-centric PER-WAVE OVERHEAD (segment setup, per-node q quant, gather
// addressing, per-step shuffles) amortized over only ~16 edges -- not the
// memory system. Fix: edge-centric score (1 lane = 1 edge, no reductions).
// Prep packs per-node int8 rows for K, V AND X(=q): 3 x 3.2 MB tables,
// plus SC = {f16 sK, f16 sV} and SCQ = f32 (sQ * log2e/32) side tables.
// dst-boundary scan (row_ptr) unchanged, int4-vectorized.
__global__ void prep_kernel(const int* __restrict__ dst,
                            const float4* __restrict__ K4,
                            const float4* __restrict__ V4,
                            const float4* __restrict__ X4,
                            int E, int N,
                            int* __restrict__ row_ptr,
                            uint4* __restrict__ K8,
                            unsigned* __restrict__ V8,
                            uint4* __restrict__ Q8,
                            unsigned* __restrict__ SC,
                            float* __restrict__ SCQ) {
    const int t  = blockIdx.x * blockDim.x + threadIdx.x;
    const int e0 = t * 4;
    if (e0 < E) {
        int cur[4];
        if (e0 + 4 <= E) {
            const int4 dd = *(const int4*)(dst + e0);
            cur[0] = dd.x; cur[1] = dd.y; cur[2] = dd.z; cur[3] = dd.w;
        } else {
#pragma unroll
            for (int k = 0; k < 4; ++k)
                cur[k] = (e0 + k < E) ? dst[e0 + k] : 0;
        }
        int prev = (e0 == 0) ? -1 : dst[e0 - 1];
#pragma unroll
        for (int k = 0; k < 4; ++k) {
            const int ee = e0 + k;
            if (ee < E) {
                for (int j = prev + 1; j <= cur[k]; ++j) row_ptr[j] = ee;
                if (ee == E - 1)
                    for (int j = cur[k] + 1; j <= N; ++j) row_ptr[j] = E;
                prev = cur[k];
            }
        }
    }
    if (t < N) {
        float4 kf[8], vf[8], xf[8];
#pragma unroll
        for (int u = 0; u < 8; ++u) {
            kf[u] = K4[t * 8 + u];
            vf[u] = V4[t * 8 + u];
            xf[u] = X4[t * 8 + u];
        }
        float mk = 0.0f, mv = 0.0f, mq = 0.0f;
#pragma unroll
        for (int u = 0; u < 8; ++u) {
            mk = fmaxf(mk, fmaxf(fmaxf(fabsf(kf[u].x), fabsf(kf[u].y)),
                                 fmaxf(fabsf(kf[u].z), fabsf(kf[u].w))));
            mv = fmaxf(mv, fmaxf(fmaxf(fabsf(vf[u].x), fabsf(vf[u].y)),
                                 fmaxf(fabsf(vf[u].z), fabsf(vf[u].w))));
            mq = fmaxf(mq, fmaxf(fmaxf(fabsf(xf[u].x), fabsf(xf[u].y)),
                                 fmaxf(fabsf(xf[u].z), fabsf(xf[u].w))));
        }
        const float rk = (mk > 0.0f) ? 127.0f / mk : 0.0f;
        const float rv = (mv > 0.0f) ? 127.0f / mv : 0.0f;
        const float rq = (mq > 0.0f) ? 127.0f / mq : 0.0f;
#pragma unroll
        for (int u2 = 0; u2 < 2; ++u2) {
            uint4 ok, oq;
            ok.x = pack8x4(kf[4 * u2],     rk);
            ok.y = pack8x4(kf[4 * u2 + 1], rk);
            ok.z = pack8x4(kf[4 * u2 + 2], rk);
            ok.w = pack8x4(kf[4 * u2 + 3], rk);
            oq.x = pack8x4(xf[4 * u2],     rq);
            oq.y = pack8x4(xf[4 * u2 + 1], rq);
            oq.z = pack8x4(xf[4 * u2 + 2], rq);
            oq.w = pack8x4(xf[4 * u2 + 3], rq);
            K8[t * 2 + u2] = ok;
            Q8[t * 2 + u2] = oq;
            uint4 ov;
            ov.x = pack8x4(vf[4 * u2],     rv);
            ov.y = pack8x4(vf[4 * u2 + 1], rv);
            ov.z = pack8x4(vf[4 * u2 + 2], rv);
            ov.w = pack8x4(vf[4 * u2 + 3], rv);
            ((uint4*)(V8 + t * 8))[u2] = ov;
        }
        h2 s;
        s.x = (_Float16)(mk * (1.0f / 127.0f));   // sK
        s.y = (_Float16)(mv * (1.0f / 127.0f));   // sV
        SC[t]  = as_u32(s);
        // sQ * log2(e)/32 pre-folded: p = si * sK * SCQ[dst]
        SCQ[t] = mq * (1.44269504f / (127.0f * 32.0f));
    }
}

// Fallback-path row_ptr builder (ws too small for packed tables).
__global__ void build_row_ptr_kernel(const int* __restrict__ dst, int E, int N,
                                     int* __restrict__ row_ptr) {
    int e = blockIdx.x * blockDim.x + threadIdx.x;
    if (e >= E) return;
    int cur  = dst[e];
    int prev = (e == 0) ? -1 : dst[e - 1];
    for (int j = prev + 1; j <= cur; ++j) row_ptr[j] = e;
    if (e == E - 1) {
        for (int j = cur + 1; j <= N; ++j) row_ptr[j] = E;
    }
}

// R20 score pass: EDGE-CENTRIC, one lane = one edge. No segments, no
// shuffles, no divergence, no per-node setup. Per lane: src/dst (coalesced),
// K8 row (2 x dwordx4, one 128B line), Q8 row (dst-sorted -> L1-hot),
// SC[src] + SCQ[dst] scales, 8 x v_dot4_i32_i8, exp2, one dword store
// {f16 w, f16 w*sV}. ~35 VALU per 64 edges vs ~250 per 16 edges in the
// node-centric form (R19's 46 us binder).
__global__ __launch_bounds__(256) void gat_score_kernel(
    const uint4* __restrict__ K8, const uint4* __restrict__ Q8,
    const unsigned* __restrict__ SC, const float* __restrict__ SCQ,
    const int* __restrict__ src, const int* __restrict__ dst,
    unsigned* __restrict__ wbuf, int E) {
    const int e  = blockIdx.x * blockDim.x + threadIdx.x;
    const int ec = min(e, E - 1);
    const int s = src[ec];
    const int d = dst[ec];
    const uint4 ka = K8[s * 2];
    const uint4 kb = K8[s * 2 + 1];
    const uint4 qa = Q8[d * 2];
    const uint4 qb = Q8[d * 2 + 1];
    const h2 scv   = as_h2(SC[s]);
    const float sq = SCQ[d];
    int si = SDOT4(ka.x, qa.x, 0);
    si = SDOT4(ka.y, qa.y, si);
    si = SDOT4(ka.z, qa.z, si);
    si = SDOT4(ka.w, qa.w, si);
    si = SDOT4(kb.x, qb.x, si);
    si = SDOT4(kb.y, qb.y, si);
    si = SDOT4(kb.z, qb.z, si);
    si = SDOT4(kb.w, qb.w, si);
    const float p  = (float)si * ((float)scv.x * sq);
    const float w  = EXP2F(p);
    const float wv = w * (float)scv.y;
    h2 o; o.x = (_Float16)w; o.y = (_Float16)wv;
    if (e < E) wbuf[e] = as_u32(o);
}

// R20 PV pass: node-centric (segment reduction forces it) but slimmed vs
// R19: no SC gather (sV pre-folded into wv at score time), no linv buffer
// (l computed inline from the coalesced w-stream), signed V8 (no bias-sum
// machinery). Per edge: 1 dword V8 gather + 1 dword wbuf stream. Verified
// MFMA projection epilogue unchanged.
__global__ __launch_bounds__(512) void gat_pv_kernel(
    const unsigned* __restrict__ V8, const int* __restrict__ src,
    const int* __restrict__ row_ptr, const unsigned* __restrict__ wbuf,
    const float* __restrict__ Wo, const float* __restrict__ bo,
    float* __restrict__ out, int N) {

    __shared__ uint4 s_part[16 * 17];   // 16-row A-tile, row stride 17 (pad)

    const int tid  = threadIdx.x;
    const int w    = tid >> 6;    // wave 0..7 = node offset in block
    const int lane = tid & 63;
    const int g    = lane >> 3;   // edge slot 0..7
    const int c    = lane & 7;    // dim chunk 0..7

    const int n_blk = blockIdx.x * 8;
    const int n     = n_blk + w;

    if (tid < 136) {                    // zero A-tile rows 8..15
        uint4 z; z.x = 0; z.y = 0; z.z = 0; z.w = 0;
        s_part[136 + tid] = z;
    }

    const int B    = __builtin_amdgcn_readfirstlane(row_ptr[min(n, N)]);
    const int En   = __builtin_amdgcn_readfirstlane(row_ptr[min(n + 1, N)]);
    const int deg  = En - B;
    const int dcap = max(En - 1, 0);
    const int T    = (deg + 7) >> 3;

    float l = 0.0f;
    f32x4 acc = {0.0f, 0.0f, 0.0f, 0.0f};

    auto step = [&](unsigned vd, unsigned wd, int t) {
        const bool valid = (t * 8 + g) < deg;
        const h2 wp = as_h2(wd);
        const float wt = valid ? (float)wp.x : 0.0f;
        const float wv = valid ? (float)wp.y : 0.0f;
        l += wt;
        acc.x = fmaf(wv, (float)(int)(char)(vd),        acc.x);
        acc.y = fmaf(wv, (float)(int)(char)(vd >> 8),   acc.y);
        acc.z = fmaf(wv, (float)(int)(char)(vd >> 16),  acc.z);
        acc.w = fmaf(wv, (float)(int)(char)(vd >> 24),  acc.w);
    };

    if (T > 0) {
        const int base = B + g;
        const int s0 = src[min(base,      dcap)];
        const int s1 = src[min(base + 8,  dcap)];
        const int s2 = src[min(base + 16, dcap)];
        const int s3 = src[min(base + 24, dcap)];
        unsigned v0 = 0, v1 = 0, v2 = 0, v3 = 0;
        unsigned w0 = 0, w1 = 0, w2 = 0, w3 = 0;
        v0 = V8[s0 * 8 + c];  w0 = wbuf[min(base, dcap)];
        if (T > 1) { v1 = V8[s1 * 8 + c];  w1 = wbuf[min(base + 8,  dcap)]; }
        if (T > 2) { v2 = V8[s2 * 8 + c];  w2 = wbuf[min(base + 16, dcap)]; }
        if (T > 3) { v3 = V8[s3 * 8 + c];  w3 = wbuf[min(base + 24, dcap)]; }

        step(v0, w0, 0);
        if (T > 1) step(v1, w1, 1);
        if (T > 2) step(v2, w2, 2);
        if (T > 3) step(v3, w3, 3);
        for (int t = 4; t < T; ++t) {     // rare deg > 32 tail
            const int e = B + t * 8 + g;
            const int sx = src[min(e, dcap)];
            step(V8[sx * 8 + c], wbuf[min(e, dcap)], t);
        }
    }

    // acc folded to slot-pair partials; l fully reduced over g
    acc.x += __shfl_xor(acc.x, 8);
    acc.y += __shfl_xor(acc.y, 8);
    acc.z += __shfl_xor(acc.z, 8);
    acc.w += __shfl_xor(acc.w, 8);
    l += __shfl_xor(l, 8);
    l += __shfl_xor(l, 16);
    l += __shfl_xor(l, 32);

    const float inv = (deg > 0) ? (1.0f / l) : 0.0f;
    h2 o01, o23;
    o01.x = (_Float16)(acc.x * inv);  o01.y = (_Float16)(acc.y * inv);
    o23.x = (_Float16)(acc.z * inv);  o23.y = (_Float16)(acc.w * inv);

    if ((g & 1) == 0) {                  // even slots hold pair sums
        unsigned* part32 = (unsigned*)s_part;
        const int off = w * 68 + (g >> 1) * 16 + c * 2;   // uint32 units
        part32[off]     = as_u32(o01);
        part32[off + 1] = as_u32(o23);
    }

    __syncthreads();

    // wave 0: projection for the block's 8 nodes via 16x16x32 f16 MFMA
    if (w == 0) {
        const int quad = lane >> 4;   // 0..3
        const int col  = lane & 15;

        union BF { h8 v; _Float16 u[8]; };
        BF bf0, bf1;
#pragma unroll
        for (int j2 = 0; j2 < 8; ++j2) {
            bf0.u[j2] = (_Float16)Wo[(quad * 8 + j2) * OUT_DIM + col];
            bf1.u[j2] = (_Float16)Wo[(quad * 8 + j2) * OUT_DIM + 16 + col];
        }
        const float bias0 = bo[col];
        const float bias1 = bo[16 + col];

        union AF { uint4 u; h8 v; };
        f32x4 C0 = {bias0, bias0, bias0, bias0};
        f32x4 C1 = {bias1, bias1, bias1, bias1};
#pragma unroll
        for (int cc = 0; cc < 4; ++cc) {
            AF a;
            a.u = s_part[col * 17 + cc * 4 + quad];      // ds_read_b128
            C0 = __builtin_amdgcn_mfma_f32_16x16x32_f16(a.v, bf0.v, C0, 0, 0, 0);
            C1 = __builtin_amdgcn_mfma_f32_16x16x32_f16(a.v, bf1.v, C1, 0, 0, 0);
        }
        // C/D layout: col = lane&15, row = quad*4 + reg (verified mapping)
        if (quad < 2) {                 // only rows 0..7 are real nodes
#pragma unroll
            for (int r = 0; r < 4; ++r) {
                const int n2 = n_blk + quad * 4 + r;
                if (n2 < N) {
                    out[n2 * OUT_DIM + col]      = C0[r];
                    out[n2 * OUT_DIM + 16 + col] = C1[r];
                }
            }
        }
    }
}

// ---- fallback (R4-proven fp32 path, used only if ws too small) ------------
__global__ __launch_bounds__(256) void gat_node_f32_kernel(
    const float* __restrict__ X, const float* __restrict__ Km,
    const float* __restrict__ Vm, const float* __restrict__ Wo,
    const float* __restrict__ bo, const int* __restrict__ src,
    const int* __restrict__ row_ptr, float* __restrict__ out, int N) {
    const int tid  = threadIdx.x;
    const int wave = tid >> 6;
    const int lane = tid & 63;
    const int g    = lane >> 3;
    const int c    = lane & 7;
    const int j    = lane & 31;
    const int half = lane >> 5;
    const int n = blockIdx.x * 4 + wave;
    if (n >= N) return;
    const int begin = row_ptr[n];
    const int end   = row_ptr[n + 1];
    const float4* X4 = (const float4*)X;
    const float4* K4 = (const float4*)Km;
    const float4* V4 = (const float4*)Vm;
    const float4 q4 = X4[n * 8 + c];
    float  l   = 0.0f;
    float4 acc = make_float4(0.0f, 0.0f, 0.0f, 0.0f);
    for (int e0 = begin; e0 < end; e0 += 16) {
        const int  ea = e0 + g;
        const int  eb = ea + 8;
        const bool va = ea < end;
        const bool vb = eb < end;
        const int sa = src[min(ea, end - 1)];
        const int sb = src[min(eb, end - 1)];
        const float4 ka  = K4[sa * 8 + c];
        const float4 kb  = K4[sb * 8 + c];
        const float4 vva = V4[sa * 8 + c];
        const float4 vvb = V4[sb * 8 + c];
        float pa = fmaf(ka.x, q4.x, fmaf(ka.y, q4.y, fmaf(ka.z, q4.z, ka.w * q4.w)));
        float pb = fmaf(kb.x, q4.x, fmaf(kb.y, q4.y, fmaf(kb.z, q4.z, kb.w * q4.w)));
        pa += __shfl_xor(pa, 1);  pb += __shfl_xor(pb, 1);
        pa += __shfl_xor(pa, 2);  pb += __shfl_xor(pb, 2);
        pa += __shfl_xor(pa, 4);  pb += __shfl_xor(pb, 4);
        const float wa = va ? __expf(pa * 0.03125f) : 0.0f;
        const float wb = vb ? __expf(pb * 0.03125f) : 0.0f;
        l += wa + wb;
        acc.x = fmaf(wa, vva.x, acc.x);  acc.y = fmaf(wa, vva.y, acc.y);
        acc.z = fmaf(wa, vva.z, acc.z);  acc.w = fmaf(wa, vva.w, acc.w);
        acc.x = fmaf(wb, vvb.x, acc.x);  acc.y = fmaf(wb, vvb.y, acc.y);
        acc.z = fmaf(wb, vvb.z, acc.z);  acc.w = fmaf(wb, vvb.w, acc.w);
    }
#pragma unroll
    for (int m = 8; m <= 32; m <<= 1) {
        l     += __shfl_xor(l, m);
        acc.x += __shfl_xor(acc.x, m);
        acc.y += __shfl_xor(acc.y, m);
        acc.z += __shfl_xor(acc.z, m);
        acc.w += __shfl_xor(acc.w, m);
    }
    const float inv = (end > begin) ? (1.0f / l) : 0.0f;
    float ag[4] = {acc.x, acc.y, acc.z, acc.w};
    float s = 0.0f;
#pragma unroll
    for (int k = 0; k < 32; ++k) {
        const float a = __int_as_float(
            __builtin_amdgcn_readlane(__float_as_int(ag[k & 3]), k >> 2));
        s = fmaf(a, Wo[k * OUT_DIM + j], s);
    }
    if (half == 0) {
        out[n * OUT_DIM + j] = fmaf(s, inv, bo[j]);
    }
}

extern "C" void kernel_launch(void* const* d_in, const int* in_sizes, int n_in,
                              void* d_out, int out_size, void* d_ws, size_t ws_size,
                              hipStream_t stream) {
    const float* X  = (const float*)d_in[0];
    const float* Km = (const float*)d_in[1];
    const float* Vm = (const float*)d_in[2];
    const float* Wo = (const float*)d_in[3];
    const float* bo = (const float*)d_in[4];
    const int* src  = (const int*)d_in[5];
    const int* dst  = (const int*)d_in[6];

    const int N = in_sizes[0] / DK;
    const int E = in_sizes[5];

    // ws: row_ptr | K8 (N*32B) | V8 (N*32B) | Q8 (N*32B) | SC (N*4B) |
    //     SCQ (N*4B) | wbuf (E*4B)
    int* row_ptr = (int*)d_ws;
    const size_t k8_off  = (((size_t)(N + 1) * 4) + 127) & ~(size_t)127;
    const size_t v8_off  = ((k8_off + (size_t)N * 32) + 127) & ~(size_t)127;
    const size_t q8_off  = ((v8_off + (size_t)N * 32) + 127) & ~(size_t)127;
    const size_t sc_off  = ((q8_off + (size_t)N * 32) + 127) & ~(size_t)127;
    const size_t sq_off  = ((sc_off + (size_t)N * 4) + 127) & ~(size_t)127;
    const size_t wb_off  = ((sq_off + (size_t)N * 4) + 127) & ~(size_t)127;
    uint4*    K8  = (uint4*)((char*)d_ws + k8_off);
    unsigned* V8  = (unsigned*)((char*)d_ws + v8_off);
    uint4*    Q8  = (uint4*)((char*)d_ws + q8_off);
    unsigned* SCt = (unsigned*)((char*)d_ws + sc_off);
    float*    SCQ = (float*)((char*)d_ws + sq_off);
    unsigned* wbuf = (unsigned*)((char*)d_ws + wb_off);
    const size_t need = wb_off + (size_t)E * 4;
    float* out = (float*)d_out;

    const int tb = 256;

    if (ws_size >= need) {
        const int nE4   = (E + 3) / 4;
        const int prep_n = (nE4 > N) ? nE4 : N;
        prep_kernel<<<(prep_n + tb - 1) / tb, tb, 0, stream>>>(
            dst, (const float4*)Km, (const float4*)Vm, (const float4*)X,
            E, N, row_ptr, K8, V8, Q8, SCt, SCQ);
        gat_score_kernel<<<(E + tb - 1) / tb, tb, 0, stream>>>(
            K8, Q8, SCt, SCQ, src, dst, wbuf, E);
        gat_pv_kernel<<<(N + 7) / 8, 512, 0, stream>>>(
            V8, src, row_ptr, wbuf, Wo, bo, out, N);
    } else {
        build_row_ptr_kernel<<<(E + tb - 1) / tb, tb, 0, stream>>>(dst, E, N, row_ptr);
        const int grid = (N + 3) / 4;
        gat_node_f32_kernel<<<grid, 256, 0, stream>>>(X, Km, Vm, Wo, bo,
                                                      src, row_ptr, out, N);
    }
}